// Round 5
// baseline (347.783 us; speedup 1.0000x reference)
//
#include <hip/hip_runtime.h>
#include <hip/hip_bf16.h>

#define T_TOK 8192
#define DDIM  1024
#define HDIM  4096
#define KCAT  8192   // 2*HDIM
#define NE    8

typedef __attribute__((ext_vector_type(8)))  __bf16 bf16x8;
typedef __attribute__((ext_vector_type(4)))  float  f32x4;
typedef __attribute__((ext_vector_type(16))) float  f32x16;

__device__ __forceinline__ unsigned short f2bf(float f) {
  union { float f; unsigned u; } v; v.f = f;
  unsigned r = v.u + 0x7fffu + ((v.u >> 16) & 1u);
  return (unsigned short)(r >> 16);
}

__device__ __forceinline__ void gl_lds16(const unsigned short* g, char* l) {
  __builtin_amdgcn_global_load_lds(
      (__attribute__((address_space(1))) const void*)g,
      (__attribute__((address_space(3))) void*)l,
      16, 0, 0);
}

// ---------------- router + x -> bf16 conversion ----------------
__global__ __launch_bounds__(256) void k_router(
    const float* __restrict__ x, const float* __restrict__ Wr,
    const float* __restrict__ br, unsigned short* __restrict__ xb,
    float* __restrict__ gates)
{
  const int lane = threadIdx.x & 63;
  const int wv   = threadIdx.x >> 6;
  const int t    = blockIdx.x * 4 + wv;
  const float* xr = x + (size_t)t * DDIM;
  unsigned short* xo = xb + (size_t)t * DDIM;

  float acc[NE];
#pragma unroll
  for (int e = 0; e < NE; ++e) acc[e] = 0.f;

#pragma unroll
  for (int i = 0; i < 4; ++i) {
    float4 v = *(const float4*)(xr + i * 256 + lane * 4);
    ushort4 o;
    o.x = f2bf(v.x); o.y = f2bf(v.y); o.z = f2bf(v.z); o.w = f2bf(v.w);
    *(ushort4*)(xo + i * 256 + lane * 4) = o;
    float vs[4] = {v.x, v.y, v.z, v.w};
#pragma unroll
    for (int j = 0; j < 4; ++j) {
      const float4* wr = (const float4*)(Wr + (size_t)(i * 256 + lane * 4 + j) * NE);
      float4 w0 = wr[0], w1 = wr[1];
      acc[0] += vs[j] * w0.x; acc[1] += vs[j] * w0.y;
      acc[2] += vs[j] * w0.z; acc[3] += vs[j] * w0.w;
      acc[4] += vs[j] * w1.x; acc[5] += vs[j] * w1.y;
      acc[6] += vs[j] * w1.z; acc[7] += vs[j] * w1.w;
    }
  }
#pragma unroll
  for (int e = 0; e < NE; ++e) {
#pragma unroll
    for (int s = 32; s > 0; s >>= 1) acc[e] += __shfl_xor(acc[e], s, 64);
  }
  if (lane == 0) {
    float lg[NE];
#pragma unroll
    for (int e = 0; e < NE; ++e) lg[e] = acc[e] + br[e];
    int a1 = 0; float m1 = lg[0];
#pragma unroll
    for (int e = 1; e < NE; ++e) if (lg[e] > m1) { m1 = lg[e]; a1 = e; }
    float m2 = -3.4e38f;
#pragma unroll
    for (int e = 0; e < NE; ++e) if (e != a1 && lg[e] > m2) m2 = lg[e];
    float g0 = 1.f / (1.f + expf(m2 - m1));
    gates[t * 2 + 0] = g0;
    gates[t * 2 + 1] = 1.f - g0;
  }
}

// ---------------- fp32 -> bf16 transpose ----------------
__global__ __launch_bounds__(256) void k_transpose(
    const float* __restrict__ in, unsigned short* __restrict__ out,
    int R, int C, int S, size_t inz, size_t outz)
{
  __shared__ float tile[32][33];
  in  += (size_t)blockIdx.z * inz;
  out += (size_t)blockIdx.z * outz;
  const int c0 = blockIdx.x * 32, r0 = blockIdx.y * 32;
  const int tx = threadIdx.x & 31, ty = threadIdx.x >> 5;
#pragma unroll
  for (int i = 0; i < 32; i += 8)
    tile[ty + i][tx] = in[(size_t)(r0 + ty + i) * C + (c0 + tx)];
  __syncthreads();
#pragma unroll
  for (int i = 0; i < 32; i += 8)
    out[(size_t)(c0 + ty + i) * S + (r0 + tx)] = f2bf(tile[tx][ty + i]);
}

// ---------------- 8-phase 256x256 MFMA GEMM, 32x32x16 frags ----------------
// C[256x256 tile] = A[M][KA]·B[N][KB]^T over K = NT*64 starting at koff=z*NT*64.
// 512 threads = 8 waves (2M x 4N), per-wave 128x64 = 4x2 32x32 frags, BK=64.
// LDS: 2 bufs x 4 regions {A-K0, A-K1, B-K0, B-K1} x 16 KiB = 128 KiB.
// Phase (kh, mh): 8 MFMA (2 mi x 2 nj x 2 ks). vmcnt(6) at phases 4/8.
// A/B frag: lane l -> row l&31, k = (l>>5)*8 + j (k-contiguous bf16x8).
// C/D frag: col = l&31, row = (reg&3) + 8*(reg>>2) + 4*(l>>5).
// MODE 0: Hout bf16 = gate_e * relu(acc + bias[col]), e = col>>12.
// MODE 1: fp32 partial (slice 0 -> P0, slice 1 -> P1).
template<int NT, int MODE>
__global__ __launch_bounds__(512, 2) void k_gemm8(
    const unsigned short* __restrict__ A,
    const unsigned short* __restrict__ B,
    unsigned short* __restrict__ Hout,
    float* __restrict__ P0, float* __restrict__ P1,
    const float* __restrict__ bias,
    const float* __restrict__ gates,
    int KA, int KB)
{
  constexpr int NIT = NT / 2;
  __shared__ __align__(16) char lds[2 * 4 * 16384];

  const int tid = threadIdx.x;
  const int l = tid & 63, l31 = l & 31, lh = l >> 5;
  const int w = tid >> 6;
  const int wm = w >> 2, wn = w & 3;

  // ---- XCD-chunked bijective swizzle (kept from R4; null but harmless) ----
  int bmIdx, bnIdx, bzIdx;
  {
    int lin = ((blockIdx.z * gridDim.y) + blockIdx.y) * gridDim.x + blockIdx.x;
    int xcd = lin & 7, slot = (lin >> 3) & 31;
    if (MODE == 0) {
      int r = lin >> 8;
      bmIdx = r * 8 + (slot >> 2);
      bnIdx = xcd * 4 + (slot & 3);
      bzIdx = 0;
    } else {
      bzIdx = xcd & 1;
      bmIdx = (xcd >> 1) * 8 + (slot >> 2);
      bnIdx = slot & 3;
    }
  }
  const int bn = bnIdx * 256;
  const int bm = bmIdx * 256;
  const int koff = bzIdx * (NT * 64);

  // staging: dest chunk tid = (row=tid>>2, c=tid&3); source chunk = c ^ ((row>>1)&3)
  const int srow = tid >> 2;
  const int sc = (tid & 3) ^ ((srow >> 1) & 3);
  const unsigned short* As = A + (size_t)(bm + srow) * KA + koff + sc * 8;
  const unsigned short* Bs = B + (size_t)(bn + srow) * KB + koff + sc * 8;

  auto stage = [&](int T, int reg) {  // reg: 0=A-K0 1=A-K1 2=B-K0 3=B-K1
    const unsigned short* src = ((reg >> 1) ? Bs : As) + T * 64 + (reg & 1) * 32;
    size_t rstride = (size_t)128 * ((reg >> 1) ? KB : KA);
    char* dst = lds + (((T & 1) * 4 + reg) << 14) + tid * 16;
    gl_lds16(src, dst);
    gl_lds16(src + rstride, dst + 8192);
  };

  // fragment LDS byte offsets (region rows: 64 B of 32 bf16 k)
  int aoff[4][2], boff[2][2];
#pragma unroll
  for (int mi = 0; mi < 4; ++mi)
#pragma unroll
    for (int ks = 0; ks < 2; ++ks) {
      int r = wm * 128 + mi * 32 + l31;
      aoff[mi][ks] = r * 64 + (((ks * 2 + lh) ^ ((r >> 1) & 3)) * 16);
    }
#pragma unroll
  for (int nj = 0; nj < 2; ++nj)
#pragma unroll
    for (int ks = 0; ks < 2; ++ks) {
      int r = wn * 64 + nj * 32 + l31;
      boff[nj][ks] = r * 64 + (((ks * 2 + lh) ^ ((r >> 1) & 3)) * 16);
    }

  f32x16 acc[4][2];
#pragma unroll
  for (int i = 0; i < 4; ++i)
#pragma unroll
    for (int j = 0; j < 2; ++j) acc[i][j] = (f32x16)(0.f);
  bf16x8 vb00, vb01, vb10, vb11;   // vb[nj][ks], persist across the mh=1 phase

  // prologue: tile0 all 4 halves + tile1 {B-K0, A-K0, B-K1}; vmcnt(6) -> tile0 landed
  stage(0, 2); stage(0, 0); stage(0, 3); stage(0, 1);
  stage(1, 2); stage(1, 0); stage(1, 3);
  asm volatile("s_waitcnt vmcnt(6)" ::: "memory");
  __builtin_amdgcn_s_barrier();

#define PH(BUF, KH, MH, VM, STG) do {                                          \
    const char* Ar_ = lds + (((BUF) * 4 + (KH)) << 14);                        \
    const char* Br_ = lds + (((BUF) * 4 + 2 + (KH)) << 14);                    \
    if ((MH) == 0) {                                                           \
      vb00 = *(const bf16x8*)(Br_ + boff[0][0]);                               \
      vb01 = *(const bf16x8*)(Br_ + boff[0][1]);                               \
      vb10 = *(const bf16x8*)(Br_ + boff[1][0]);                               \
      vb11 = *(const bf16x8*)(Br_ + boff[1][1]);                               \
    }                                                                          \
    bf16x8 va00 = *(const bf16x8*)(Ar_ + aoff[(MH)*2+0][0]);                   \
    bf16x8 va01 = *(const bf16x8*)(Ar_ + aoff[(MH)*2+0][1]);                   \
    bf16x8 va10 = *(const bf16x8*)(Ar_ + aoff[(MH)*2+1][0]);                   \
    bf16x8 va11 = *(const bf16x8*)(Ar_ + aoff[(MH)*2+1][1]);                   \
    STG;                                                                       \
    if ((VM) == 6) asm volatile("s_waitcnt vmcnt(6)" ::: "memory");            \
    else if ((VM) == 0) asm volatile("s_waitcnt vmcnt(0)" ::: "memory");       \
    __builtin_amdgcn_s_barrier();                                              \
    asm volatile("s_waitcnt lgkmcnt(0)" ::: "memory");                         \
    __builtin_amdgcn_s_setprio(1);                                             \
    acc[(MH)*2+0][0] = __builtin_amdgcn_mfma_f32_32x32x16_bf16(va00, vb00, acc[(MH)*2+0][0], 0,0,0); \
    acc[(MH)*2+0][1] = __builtin_amdgcn_mfma_f32_32x32x16_bf16(va00, vb10, acc[(MH)*2+0][1], 0,0,0); \
    acc[(MH)*2+1][0] = __builtin_amdgcn_mfma_f32_32x32x16_bf16(va10, vb00, acc[(MH)*2+1][0], 0,0,0); \
    acc[(MH)*2+1][1] = __builtin_amdgcn_mfma_f32_32x32x16_bf16(va10, vb10, acc[(MH)*2+1][1], 0,0,0); \
    acc[(MH)*2+0][0] = __builtin_amdgcn_mfma_f32_32x32x16_bf16(va01, vb01, acc[(MH)*2+0][0], 0,0,0); \
    acc[(MH)*2+0][1] = __builtin_amdgcn_mfma_f32_32x32x16_bf16(va01, vb11, acc[(MH)*2+0][1], 0,0,0); \
    acc[(MH)*2+1][0] = __builtin_amdgcn_mfma_f32_32x32x16_bf16(va11, vb01, acc[(MH)*2+1][0], 0,0,0); \
    acc[(MH)*2+1][1] = __builtin_amdgcn_mfma_f32_32x32x16_bf16(va11, vb11, acc[(MH)*2+1][1], 0,0,0); \
    __builtin_amdgcn_s_setprio(0);                                             \
    __builtin_amdgcn_s_barrier();                                              \
  } while (0)

  for (int t = 0; t < NIT - 1; ++t) {
    PH(0, 0, 0, -1, stage(2 * t + 1, 1));
    PH(0, 0, 1, -1, stage(2 * t + 2, 2));
    PH(0, 1, 0, -1, stage(2 * t + 2, 0));
    PH(0, 1, 1,  6, stage(2 * t + 2, 3));
    PH(1, 0, 0, -1, stage(2 * t + 2, 1));
    PH(1, 0, 1, -1, stage(2 * t + 3, 2));
    PH(1, 1, 0, -1, stage(2 * t + 3, 0));
    PH(1, 1, 1,  6, stage(2 * t + 3, 3));
  }
  PH(0, 0, 0, -1, stage(NT - 1, 1));
  PH(0, 0, 1, -1, ;);
  PH(0, 1, 0, -1, ;);
  PH(0, 1, 1,  0, ;);
  PH(1, 0, 0, -1, ;);
  PH(1, 0, 1, -1, ;);
  PH(1, 1, 0, -1, ;);
  PH(1, 1, 1, -1, ;);
#undef PH

  // epilogue; C/D map: col = l31, row = (reg&3) + 8*(reg>>2) + 4*lh
  if constexpr (MODE == 0) {
    const int ge = bn >> 12;
    float bcol[2];
    int colg[2];
#pragma unroll
    for (int nj = 0; nj < 2; ++nj) {
      colg[nj] = bn + wn * 64 + nj * 32 + l31;
      bcol[nj] = bias[colg[nj]];
    }
#pragma unroll
    for (int mi = 0; mi < 4; ++mi) {
#pragma unroll
      for (int reg = 0; reg < 16; ++reg) {
        int row = bm + wm * 128 + mi * 32 + (reg & 3) + 8 * (reg >> 2) + 4 * lh;
        float gate = gates[row * 2 + ge];
        size_t rb = (size_t)row * KCAT;
#pragma unroll
        for (int nj = 0; nj < 2; ++nj) {
          float v = acc[mi][nj][reg] + bcol[nj];
          Hout[rb + colg[nj]] = f2bf(fmaxf(v, 0.f) * gate);
        }
      }
    }
  } else {
    float* P = bzIdx ? P1 : P0;
    int colg[2];
#pragma unroll
    for (int nj = 0; nj < 2; ++nj) colg[nj] = bn + wn * 64 + nj * 32 + l31;
#pragma unroll
    for (int mi = 0; mi < 4; ++mi) {
#pragma unroll
      for (int reg = 0; reg < 16; ++reg) {
        int row = bm + wm * 128 + mi * 32 + (reg & 3) + 8 * (reg >> 2) + 4 * lh;
        size_t rb = (size_t)row * DDIM;
#pragma unroll
        for (int nj = 0; nj < 2; ++nj) P[rb + colg[nj]] = acc[mi][nj][reg];
      }
    }
  }
}

// ---------------- combine: out = p0 + p1 + g0*b2[0] + g1*b2[1] ----------------
__global__ __launch_bounds__(256) void k_combine(
    const float* __restrict__ P1, const float* __restrict__ b2,
    const float* __restrict__ gates, float* __restrict__ O)
{
  size_t i = ((size_t)blockIdx.x * 256 + threadIdx.x) * 4;
  int row = (int)(i >> 10), d = (int)(i & 1023);
  float g0 = gates[row * 2], g1 = gates[row * 2 + 1];
  float4 p0 = *(const float4*)(O + i);
  float4 p1 = *(const float4*)(P1 + i);
  float4 ba = *(const float4*)(b2 + d);
  float4 bb = *(const float4*)(b2 + DDIM + d);
  float4 r;
  r.x = p0.x + p1.x + g0 * ba.x + g1 * bb.x;
  r.y = p0.y + p1.y + g0 * ba.y + g1 * bb.y;
  r.z = p0.z + p1.z + g0 * ba.z + g1 * bb.z;
  r.w = p0.w + p1.w + g0 * ba.w + g1 * bb.w;
  *(float4*)(O + i) = r;
}

extern "C" void kernel_launch(void* const* d_in, const int* in_sizes, int n_in,
                              void* d_out, int out_size, void* d_ws, size_t ws_size,
                              hipStream_t stream) {
  const float* x  = (const float*)d_in[0];
  const float* Wr = (const float*)d_in[1];
  const float* br = (const float*)d_in[2];
  const float* W1 = (const float*)d_in[3];
  const float* b1 = (const float*)d_in[4];
  const float* W2 = (const float*)d_in[5];
  const float* b2 = (const float*)d_in[6];

  char* ws = (char*)d_ws;
  unsigned short* xb    = (unsigned short*)(ws);               // [0,16M)  x bf16
  unsigned short* W1T   = (unsigned short*)(ws + (16u << 20)); // [16,32M) [8192][1024]
  unsigned short* W2T   = (unsigned short*)(ws + (32u << 20)); // [32,48M) [1024][8192]
  float*          gates = (float*)(ws + (48u << 20));          // [48M,+64K)
  unsigned short* hbuf  = (unsigned short*)(ws + (49u << 20)); // [49,177M) [8192][8192]
  float*          P1    = (float*)(ws);                        // reuses xb+W1T after GEMM1

  k_router<<<dim3(T_TOK / 4), dim3(256), 0, stream>>>(x, Wr, br, xb, gates);

  k_transpose<<<dim3(HDIM / 32, DDIM / 32, 2), dim3(256), 0, stream>>>(
      W1, W1T, DDIM, HDIM, DDIM, (size_t)DDIM * HDIM, (size_t)HDIM * DDIM);
  k_transpose<<<dim3(DDIM / 32, HDIM / 32, 2), dim3(256), 0, stream>>>(
      W2, W2T, HDIM, DDIM, KCAT, (size_t)HDIM * DDIM, (size_t)HDIM);

  // layer1: 8192x8192x1024 (experts concat over N)
  k_gemm8<16, 0><<<dim3(KCAT / 256, T_TOK / 256, 1), dim3(512), 0, stream>>>(
      xb, W1T, hbuf, nullptr, nullptr, b1, gates, DDIM, DDIM);

  // layer2: 8192x1024x8192, split-K=2 at the expert boundary
  k_gemm8<64, 1><<<dim3(DDIM / 256, T_TOK / 256, 2), dim3(512), 0, stream>>>(
      hbuf, W2T, nullptr, (float*)d_out, P1, nullptr, nullptr, KCAT, KCAT);

  k_combine<<<dim3(T_TOK * DDIM / 4 / 256), dim3(256), 0, stream>>>(
      P1, b2, gates, (float*)d_out);
}

// Round 6
// 323.358 us; speedup vs baseline: 1.0755x; 1.0755x over previous
//
#include <hip/hip_runtime.h>
#include <hip/hip_bf16.h>

#define T_TOK 8192
#define DDIM  1024
#define HDIM  4096
#define KCAT  8192   // 2*HDIM
#define NE    8

typedef __attribute__((ext_vector_type(8))) __bf16 bf16x8;
typedef __attribute__((ext_vector_type(4))) float  f32x4;

__device__ __forceinline__ unsigned short f2bf(float f) {
  union { float f; unsigned u; } v; v.f = f;
  unsigned r = v.u + 0x7fffu + ((v.u >> 16) & 1u);
  return (unsigned short)(r >> 16);
}

__device__ __forceinline__ void gl_lds16(const unsigned short* g, char* l) {
  __builtin_amdgcn_global_load_lds(
      (__attribute__((address_space(1))) const void*)g,
      (__attribute__((address_space(3))) void*)l,
      16, 0, 0);
}

// ---------------- router + x -> bf16 conversion ----------------
__global__ __launch_bounds__(256) void k_router(
    const float* __restrict__ x, const float* __restrict__ Wr,
    const float* __restrict__ br, unsigned short* __restrict__ xb,
    float* __restrict__ gates)
{
  const int lane = threadIdx.x & 63;
  const int wv   = threadIdx.x >> 6;
  const int t    = blockIdx.x * 4 + wv;
  const float* xr = x + (size_t)t * DDIM;
  unsigned short* xo = xb + (size_t)t * DDIM;

  float acc[NE];
#pragma unroll
  for (int e = 0; e < NE; ++e) acc[e] = 0.f;

#pragma unroll
  for (int i = 0; i < 4; ++i) {
    float4 v = *(const float4*)(xr + i * 256 + lane * 4);
    ushort4 o;
    o.x = f2bf(v.x); o.y = f2bf(v.y); o.z = f2bf(v.z); o.w = f2bf(v.w);
    *(ushort4*)(xo + i * 256 + lane * 4) = o;
    float vs[4] = {v.x, v.y, v.z, v.w};
#pragma unroll
    for (int j = 0; j < 4; ++j) {
      const float4* wr = (const float4*)(Wr + (size_t)(i * 256 + lane * 4 + j) * NE);
      float4 w0 = wr[0], w1 = wr[1];
      acc[0] += vs[j] * w0.x; acc[1] += vs[j] * w0.y;
      acc[2] += vs[j] * w0.z; acc[3] += vs[j] * w0.w;
      acc[4] += vs[j] * w1.x; acc[5] += vs[j] * w1.y;
      acc[6] += vs[j] * w1.z; acc[7] += vs[j] * w1.w;
    }
  }
#pragma unroll
  for (int e = 0; e < NE; ++e) {
#pragma unroll
    for (int s = 32; s > 0; s >>= 1) acc[e] += __shfl_xor(acc[e], s, 64);
  }
  if (lane == 0) {
    float lg[NE];
#pragma unroll
    for (int e = 0; e < NE; ++e) lg[e] = acc[e] + br[e];
    int a1 = 0; float m1 = lg[0];
#pragma unroll
    for (int e = 1; e < NE; ++e) if (lg[e] > m1) { m1 = lg[e]; a1 = e; }
    float m2 = -3.4e38f;
#pragma unroll
    for (int e = 0; e < NE; ++e) if (e != a1 && lg[e] > m2) m2 = lg[e];
    float g0 = 1.f / (1.f + expf(m2 - m1));
    gates[t * 2 + 0] = g0;
    gates[t * 2 + 1] = 1.f - g0;
  }
}

// ---------------- fp32 -> bf16 transpose ----------------
__global__ __launch_bounds__(256) void k_transpose(
    const float* __restrict__ in, unsigned short* __restrict__ out,
    int R, int C, int S, size_t inz, size_t outz)
{
  __shared__ float tile[32][33];
  in  += (size_t)blockIdx.z * inz;
  out += (size_t)blockIdx.z * outz;
  const int c0 = blockIdx.x * 32, r0 = blockIdx.y * 32;
  const int tx = threadIdx.x & 31, ty = threadIdx.x >> 5;
#pragma unroll
  for (int i = 0; i < 32; i += 8)
    tile[ty + i][tx] = in[(size_t)(r0 + ty + i) * C + (c0 + tx)];
  __syncthreads();
#pragma unroll
  for (int i = 0; i < 32; i += 8)
    out[(size_t)(c0 + ty + i) * S + (r0 + tx)] = f2bf(tile[tx][ty + i]);
}

// ---------------- 8-phase 256x256 MFMA GEMM (16x16x32 frags) ----------------
// C[256x256 tile] = A[M][KA]·B[N][KB]^T over K = NT*64 starting at koff=z*NT*64.
// 512 threads = 8 waves (2M x 4N), per-wave 128x64, BK=64.
// LDS: 2 bufs x 4 regions {A-K0, A-K1, B-K0, B-K1} x 16 KiB = 128 KiB.
// PH0 (mh=0): issues 12 ds_reads (B + A[mh0] + prefetch A[mh1]), then MFMA mh0.
// PH1 (mh=1): ZERO ds_reads — pure MFMA on prefetched regs. The hoisted A1
// reads drain under PH0's MFMA shadow -> LDS port overlaps the matrix pipe.
// Compiler emits counted lgkmcnt from data deps (no manual waitcnt).
// vmcnt(6) at phases 4/8 keeps 3 half-tiles in flight (T4).
template<int NT, int MODE>
__global__ __launch_bounds__(512, 2) void k_gemm8(
    const unsigned short* __restrict__ A,
    const unsigned short* __restrict__ B,
    unsigned short* __restrict__ Hout,
    float* __restrict__ P0, float* __restrict__ P1,
    const float* __restrict__ bias,
    const float* __restrict__ gates,
    int KA, int KB)
{
  constexpr int NIT = NT / 2;
  __shared__ __align__(16) char lds[2 * 4 * 16384];

  const int tid = threadIdx.x;
  const int l = tid & 63, g = (l >> 4), l15 = l & 15;
  const int w = tid >> 6;
  const int wm = w >> 2, wn = w & 3;

  // ---- XCD-chunked bijective swizzle (null per R4 A/B, kept constant) ----
  int bmIdx, bnIdx, bzIdx;
  {
    int lin = ((blockIdx.z * gridDim.y) + blockIdx.y) * gridDim.x + blockIdx.x;
    int xcd = lin & 7, slot = (lin >> 3) & 31;
    if (MODE == 0) {
      int r = lin >> 8;
      bmIdx = r * 8 + (slot >> 2);
      bnIdx = xcd * 4 + (slot & 3);
      bzIdx = 0;
    } else {
      bzIdx = xcd & 1;
      bmIdx = (xcd >> 1) * 8 + (slot >> 2);
      bnIdx = slot & 3;
    }
  }
  const int bn = bnIdx * 256;
  const int bm = bmIdx * 256;
  const int koff = bzIdx * (NT * 64);

  // staging: dest chunk tid = (row=tid>>2, c=tid&3); source chunk = c ^ ((row>>1)&3)
  const int srow = tid >> 2;
  const int sc = (tid & 3) ^ ((srow >> 1) & 3);
  const unsigned short* As = A + (size_t)(bm + srow) * KA + koff + sc * 8;
  const unsigned short* Bs = B + (size_t)(bn + srow) * KB + koff + sc * 8;

  auto stage = [&](int T, int reg) {  // reg: 0=A-K0 1=A-K1 2=B-K0 3=B-K1
    const unsigned short* src = ((reg >> 1) ? Bs : As) + T * 64 + (reg & 1) * 32;
    size_t rstride = (size_t)128 * ((reg >> 1) ? KB : KA);
    char* dst = lds + (((T & 1) * 4 + reg) << 14) + tid * 16;
    gl_lds16(src, dst);
    gl_lds16(src + rstride, dst + 8192);
  };

  // fragment LDS byte offsets (region rows: 64 B of 32 bf16 k)
  int aoff[2][4], boff[4];
#pragma unroll
  for (int mh = 0; mh < 2; ++mh)
#pragma unroll
    for (int mi = 0; mi < 4; ++mi) {
      int r = wm * 128 + mh * 64 + mi * 16 + l15;
      aoff[mh][mi] = r * 64 + ((g ^ ((r >> 1) & 3)) * 16);
    }
#pragma unroll
  for (int nj = 0; nj < 4; ++nj) {
    int r = wn * 64 + nj * 16 + l15;
    boff[nj] = r * 64 + ((g ^ ((r >> 1) & 3)) * 16);
  }

  f32x4 acc[8][4];
#pragma unroll
  for (int i = 0; i < 8; ++i)
#pragma unroll
    for (int j = 0; j < 4; ++j) acc[i][j] = (f32x4){0.f, 0.f, 0.f, 0.f};
  bf16x8 vb0, vb1, vb2, vb3;       // B frags, live across PH0+PH1
  bf16x8 vn0, vn1, vn2, vn3;       // prefetched A[mh=1] frags

  // prologue: tile0 all 4 halves + tile1 {B-K0, A-K0, B-K1}; vmcnt(6) -> tile0 landed
  stage(0, 2); stage(0, 0); stage(0, 3); stage(0, 1);
  stage(1, 2); stage(1, 0); stage(1, 3);
  asm volatile("s_waitcnt vmcnt(6)" ::: "memory");
  __builtin_amdgcn_s_barrier();

#define MFMA16(AI, A0, A1, A2, A3)                                                     \
    acc[(AI)+0][0] = __builtin_amdgcn_mfma_f32_16x16x32_bf16(A0, vb0, acc[(AI)+0][0], 0,0,0); \
    acc[(AI)+0][1] = __builtin_amdgcn_mfma_f32_16x16x32_bf16(A0, vb1, acc[(AI)+0][1], 0,0,0); \
    acc[(AI)+0][2] = __builtin_amdgcn_mfma_f32_16x16x32_bf16(A0, vb2, acc[(AI)+0][2], 0,0,0); \
    acc[(AI)+0][3] = __builtin_amdgcn_mfma_f32_16x16x32_bf16(A0, vb3, acc[(AI)+0][3], 0,0,0); \
    acc[(AI)+1][0] = __builtin_amdgcn_mfma_f32_16x16x32_bf16(A1, vb0, acc[(AI)+1][0], 0,0,0); \
    acc[(AI)+1][1] = __builtin_amdgcn_mfma_f32_16x16x32_bf16(A1, vb1, acc[(AI)+1][1], 0,0,0); \
    acc[(AI)+1][2] = __builtin_amdgcn_mfma_f32_16x16x32_bf16(A1, vb2, acc[(AI)+1][2], 0,0,0); \
    acc[(AI)+1][3] = __builtin_amdgcn_mfma_f32_16x16x32_bf16(A1, vb3, acc[(AI)+1][3], 0,0,0); \
    acc[(AI)+2][0] = __builtin_amdgcn_mfma_f32_16x16x32_bf16(A2, vb0, acc[(AI)+2][0], 0,0,0); \
    acc[(AI)+2][1] = __builtin_amdgcn_mfma_f32_16x16x32_bf16(A2, vb1, acc[(AI)+2][1], 0,0,0); \
    acc[(AI)+2][2] = __builtin_amdgcn_mfma_f32_16x16x32_bf16(A2, vb2, acc[(AI)+2][2], 0,0,0); \
    acc[(AI)+2][3] = __builtin_amdgcn_mfma_f32_16x16x32_bf16(A2, vb3, acc[(AI)+2][3], 0,0,0); \
    acc[(AI)+3][0] = __builtin_amdgcn_mfma_f32_16x16x32_bf16(A3, vb0, acc[(AI)+3][0], 0,0,0); \
    acc[(AI)+3][1] = __builtin_amdgcn_mfma_f32_16x16x32_bf16(A3, vb1, acc[(AI)+3][1], 0,0,0); \
    acc[(AI)+3][2] = __builtin_amdgcn_mfma_f32_16x16x32_bf16(A3, vb2, acc[(AI)+3][2], 0,0,0); \
    acc[(AI)+3][3] = __builtin_amdgcn_mfma_f32_16x16x32_bf16(A3, vb3, acc[(AI)+3][3], 0,0,0);

  // PH0: mh=0 phase — 12 ds_reads (B, A0, prefetch A1), then MFMA mh0.
#define PH0(BUF, KH, VM, STG) do {                                             \
    const char* Ar_ = lds + (((BUF) * 4 + (KH)) << 14);                        \
    const char* Br_ = lds + (((BUF) * 4 + 2 + (KH)) << 14);                    \
    vb0 = *(const bf16x8*)(Br_ + boff[0]);                                     \
    vb1 = *(const bf16x8*)(Br_ + boff[1]);                                     \
    vb2 = *(const bf16x8*)(Br_ + boff[2]);                                     \
    vb3 = *(const bf16x8*)(Br_ + boff[3]);                                     \
    bf16x8 vc0 = *(const bf16x8*)(Ar_ + aoff[0][0]);                           \
    bf16x8 vc1 = *(const bf16x8*)(Ar_ + aoff[0][1]);                           \
    bf16x8 vc2 = *(const bf16x8*)(Ar_ + aoff[0][2]);                           \
    bf16x8 vc3 = *(const bf16x8*)(Ar_ + aoff[0][3]);                           \
    vn0 = *(const bf16x8*)(Ar_ + aoff[1][0]);                                  \
    vn1 = *(const bf16x8*)(Ar_ + aoff[1][1]);                                  \
    vn2 = *(const bf16x8*)(Ar_ + aoff[1][2]);                                  \
    vn3 = *(const bf16x8*)(Ar_ + aoff[1][3]);                                  \
    asm volatile("" ::: "memory");  /* pin read issue before barrier */        \
    STG;                                                                       \
    if ((VM) == 6) asm volatile("s_waitcnt vmcnt(6)" ::: "memory");            \
    else if ((VM) == 0) asm volatile("s_waitcnt vmcnt(0)" ::: "memory");       \
    __builtin_amdgcn_s_barrier();                                              \
    __builtin_amdgcn_s_setprio(1);                                             \
    MFMA16(0, vc0, vc1, vc2, vc3)                                              \
    __builtin_amdgcn_s_setprio(0);                                             \
    __builtin_amdgcn_s_barrier();                                              \
  } while (0)

  // PH1: mh=1 phase — zero ds_reads, pure MFMA on prefetched vn*.
#define PH1(VM, STG) do {                                                      \
    STG;                                                                       \
    if ((VM) == 6) asm volatile("s_waitcnt vmcnt(6)" ::: "memory");            \
    else if ((VM) == 0) asm volatile("s_waitcnt vmcnt(0)" ::: "memory");       \
    __builtin_amdgcn_s_barrier();                                              \
    __builtin_amdgcn_s_setprio(1);                                             \
    MFMA16(4, vn0, vn1, vn2, vn3)                                              \
    __builtin_amdgcn_s_setprio(0);                                             \
    __builtin_amdgcn_s_barrier();                                              \
  } while (0)

  for (int t = 0; t < NIT - 1; ++t) {
    PH0(0, 0, -1, stage(2 * t + 1, 1));
    PH1(      -1, stage(2 * t + 2, 2));
    PH0(0, 1, -1, stage(2 * t + 2, 0));
    PH1(       6, stage(2 * t + 2, 3));
    PH0(1, 0, -1, stage(2 * t + 2, 1));
    PH1(      -1, stage(2 * t + 3, 2));
    PH0(1, 1, -1, stage(2 * t + 3, 0));
    PH1(       6, stage(2 * t + 3, 3));
  }
  // final iteration: only the odd tile's A-K1 remains to stage
  PH0(0, 0, -1, stage(NT - 1, 1));
  PH1(      -1, ;);
  PH0(0, 1, -1, ;);
  PH1(       0, ;);
  PH0(1, 0, -1, ;);
  PH1(      -1, ;);
  PH0(1, 1, -1, ;);
  PH1(      -1, ;);
#undef PH0
#undef PH1
#undef MFMA16

  // epilogue; C/D map: col = l&15, row = (l>>4)*4 + rr
  if constexpr (MODE == 0) {
    const int ge = bn >> 12;
    float bcol[4];
#pragma unroll
    for (int nj = 0; nj < 4; ++nj) bcol[nj] = bias[bn + wn * 64 + nj * 16 + l15];
#pragma unroll
    for (int mi = 0; mi < 8; ++mi) {
#pragma unroll
      for (int rr = 0; rr < 4; ++rr) {
        int row = bm + wm * 128 + mi * 16 + g * 4 + rr;
        float gate = gates[row * 2 + ge];
        size_t rb = (size_t)row * KCAT + bn + wn * 64 + l15;
#pragma unroll
        for (int nj = 0; nj < 4; ++nj) {
          float v = acc[mi][nj][rr] + bcol[nj];
          Hout[rb + nj * 16] = f2bf(fmaxf(v, 0.f) * gate);
        }
      }
    }
  } else {
    float* P = bzIdx ? P1 : P0;
#pragma unroll
    for (int mi = 0; mi < 8; ++mi) {
#pragma unroll
      for (int rr = 0; rr < 4; ++rr) {
        int row = bm + wm * 128 + mi * 16 + g * 4 + rr;
        size_t rb = (size_t)row * DDIM + bn + wn * 64 + l15;
#pragma unroll
        for (int nj = 0; nj < 4; ++nj) P[rb + nj * 16] = acc[mi][nj][rr];
      }
    }
  }
}

// ---------------- combine: out = p0 + p1 + g0*b2[0] + g1*b2[1] ----------------
__global__ __launch_bounds__(256) void k_combine(
    const float* __restrict__ P1, const float* __restrict__ b2,
    const float* __restrict__ gates, float* __restrict__ O)
{
  size_t i = ((size_t)blockIdx.x * 256 + threadIdx.x) * 4;
  int row = (int)(i >> 10), d = (int)(i & 1023);
  float g0 = gates[row * 2], g1 = gates[row * 2 + 1];
  float4 p0 = *(const float4*)(O + i);
  float4 p1 = *(const float4*)(P1 + i);
  float4 ba = *(const float4*)(b2 + d);
  float4 bb = *(const float4*)(b2 + DDIM + d);
  float4 r;
  r.x = p0.x + p1.x + g0 * ba.x + g1 * bb.x;
  r.y = p0.y + p1.y + g0 * ba.y + g1 * bb.y;
  r.z = p0.z + p1.z + g0 * ba.z + g1 * bb.z;
  r.w = p0.w + p1.w + g0 * ba.w + g1 * bb.w;
  *(float4*)(O + i) = r;
}

extern "C" void kernel_launch(void* const* d_in, const int* in_sizes, int n_in,
                              void* d_out, int out_size, void* d_ws, size_t ws_size,
                              hipStream_t stream) {
  const float* x  = (const float*)d_in[0];
  const float* Wr = (const float*)d_in[1];
  const float* br = (const float*)d_in[2];
  const float* W1 = (const float*)d_in[3];
  const float* b1 = (const float*)d_in[4];
  const float* W2 = (const float*)d_in[5];
  const float* b2 = (const float*)d_in[6];

  char* ws = (char*)d_ws;
  unsigned short* xb    = (unsigned short*)(ws);               // [0,16M)  x bf16
  unsigned short* W1T   = (unsigned short*)(ws + (16u << 20)); // [16,32M) [8192][1024]
  unsigned short* W2T   = (unsigned short*)(ws + (32u << 20)); // [32,48M) [1024][8192]
  float*          gates = (float*)(ws + (48u << 20));          // [48M,+64K)
  unsigned short* hbuf  = (unsigned short*)(ws + (49u << 20)); // [49,177M) [8192][8192]
  float*          P1    = (float*)(ws);                        // reuses xb+W1T after GEMM1

  k_router<<<dim3(T_TOK / 4), dim3(256), 0, stream>>>(x, Wr, br, xb, gates);

  k_transpose<<<dim3(HDIM / 32, DDIM / 32, 2), dim3(256), 0, stream>>>(
      W1, W1T, DDIM, HDIM, DDIM, (size_t)DDIM * HDIM, (size_t)HDIM * DDIM);
  k_transpose<<<dim3(DDIM / 32, HDIM / 32, 2), dim3(256), 0, stream>>>(
      W2, W2T, HDIM, DDIM, KCAT, (size_t)HDIM * DDIM, (size_t)HDIM);

  // layer1: 8192x8192x1024 (experts concat over N)
  k_gemm8<16, 0><<<dim3(KCAT / 256, T_TOK / 256, 1), dim3(512), 0, stream>>>(
      xb, W1T, hbuf, nullptr, nullptr, b1, gates, DDIM, DDIM);

  // layer2: 8192x1024x8192, split-K=2 at the expert boundary
  k_gemm8<64, 1><<<dim3(DDIM / 256, T_TOK / 256, 2), dim3(512), 0, stream>>>(
      hbuf, W2T, nullptr, (float*)d_out, P1, nullptr, nullptr, KCAT, KCAT);

  k_combine<<<dim3(T_TOK * DDIM / 4 / 256), dim3(256), 0, stream>>>(
      P1, b2, gates, (float*)d_out);
}